// Round 3
// baseline (2050.188 us; speedup 1.0000x reference)
//
#include <hip/hip_runtime.h>

#define N_ROWS 131072
#define DIM 64
#define K_CODES 4096
#define BROWS 256            // rows per block = 4 waves x 64
#define CK 64                // cols per chunk
#define NCH (K_CODES / CK)   // 64 chunks
#define EPS 0.015625f        // flag margin in score space (>=15x bf16x3 error bound)
#define HEPS 0.0078125f      // EPS/2 in d-space (score = -2*d)

typedef __attribute__((ext_vector_type(8))) short short8;
typedef __attribute__((ext_vector_type(4))) float f32x4;

__device__ inline unsigned short bf16rn(float f) {      // round-nearest-even
    unsigned int u = __float_as_uint(f);
    u += 0x7FFFu + ((u >> 16) & 1u);
    return (unsigned short)(u >> 16);
}
// order-preserving float -> uint32 (finite scores)
__device__ inline unsigned int fkey(float f) {
    unsigned int u = __float_as_uint(f);
    return (u & 0x80000000u) ? ~u : (u | 0x80000000u);
}

__device__ __forceinline__ void gll16(const void* g, void* l) {
    __builtin_amdgcn_global_load_lds(
        (const __attribute__((address_space(1))) void*)g,
        (__attribute__((address_space(3))) void*)l, 16, 0, 0);
}

// ---- e2[k] = sum_d embed[k][d]^2 (exact fp32) ----
__global__ void e2_kernel(const float* __restrict__ embed, float* __restrict__ e2) {
    int k = blockIdx.x * blockDim.x + threadIdx.x;
    const float4* e = reinterpret_cast<const float4*>(embed + (size_t)k * DIM);
    float s = 0.f;
#pragma unroll
    for (int i = 0; i < DIM / 4; ++i) {
        float4 v = e[i];
        s = fmaf(v.x, v.x, s);
        s = fmaf(v.y, v.y, s);
        s = fmaf(v.z, v.z, s);
        s = fmaf(v.w, v.w, s);
    }
    e2[k] = s;
}

// ---- pack embed -> bf16 hi/lo "LDS images", one 16KB image per chunk ----
// Image layout per chunk: bytes [0,8192) = hi half, [8192,16384) = lo half.
// Within each half, phys byte p holds logical byte L = p ^ (((p>>7)&7)<<4)
// of a row-major [64 codes][64 bf16] tile (XOR swizzle keeps ds_read_b128
// bank-even; 16B granules map to 16B granules so linear global_load_lds works).
__global__ void pack_kernel(const float* __restrict__ embed,
                            unsigned short* __restrict__ ebf) {
    const int g = blockIdx.x * blockDim.x + threadIdx.x;   // granule id (16B each)
    const int ch  = g >> 10;                               // 1024 granules / chunk
    const int off = (g & 1023) << 4;                       // byte in 16KB image
    const int lohalf = off >> 13;                          // 0 = hi, 1 = lo
    const int p = off & 8191;
    const int L = p ^ (((p >> 7) & 7) << 4);
    const int row = L >> 7;
    const int d0  = (L & 127) >> 1;
    const float* ep = embed + ((size_t)(ch * 64 + row) * DIM + d0);
    float4 f0 = *(const float4*)ep;
    float4 f1 = *(const float4*)(ep + 4);
    float w[8] = {f0.x, f0.y, f0.z, f0.w, f1.x, f1.y, f1.z, f1.w};
    unsigned short o[8];
#pragma unroll
    for (int j = 0; j < 8; ++j) {
        unsigned short hb = bf16rn(w[j]);
        if (lohalf == 0) {
            o[j] = hb;
        } else {
            float hf = __uint_as_float(((unsigned int)hb) << 16);
            o[j] = bf16rn(w[j] - hf);
        }
    }
    *(uint4*)(ebf + (size_t)g * 8) = *(uint4*)o;
}

// ---- MFMA distance + fused top-2 argmax(dot - e2/2) ----
// Wave = 64 rows; A (xh,xl frags) in registers for the whole sweep.
// B tiles DMA'd via global_load_lds (double-buffered, prefetch-early/drain-late).
// acc init = -e2/2, then acc += xh*eh + xh*el + xl*eh (bf16x3); score = -2*acc.
__global__ __launch_bounds__(256, 2) void dist_argmin_kernel(
        const float* __restrict__ x, const unsigned short* __restrict__ ebf,
        const float* __restrict__ e2g, int* __restrict__ ind_ws,
        float* __restrict__ ind_out, int* __restrict__ cnt,
        int* __restrict__ list) {
    __shared__ unsigned short ebuf[2][8192];   // 2 x 16KB chunk images
    __shared__ float e2l[K_CODES];             // 16KB

    const int tid  = threadIdx.x;
    const int l15  = tid & 15;
    const int quad = (tid >> 4) & 3;
    const int wave = tid >> 6;
    const int r0w  = blockIdx.x * BROWS + wave * 64;

    const int lane16 = (tid & 63) << 4;
    const int uoff   = wave << 10;
    const char* ebfB = (const char*)ebf;
    char* lds0 = (char*)&ebuf[0][0];

#define STAGE(CH, BUF) do {                                              \
        const char* _g = ebfB + ((size_t)(CH) << 14) + uoff + lane16;    \
        char* _l = lds0 + ((BUF) << 14) + uoff;                          \
        gll16(_g,         _l);                                           \
        gll16(_g + 4096,  _l + 4096);                                    \
        gll16(_g + 8192,  _l + 8192);                                    \
        gll16(_g + 12288, _l + 12288);                                   \
    } while (0)

    // issue chunk-0 DMA first so it flies under the prologue work
    STAGE(0, 0);

    // e2 -> LDS (one-time)
    {
        const float4* s = (const float4*)e2g;
        float4* d = (float4*)e2l;
        for (int i = tid; i < K_CODES / 4; i += 256) d[i] = s[i];
    }

    // A-frags: A[m=l15][k=quad*8+j] per 16x16x32; rows 16i+l15, k-windows 32s+8q
    short8 ah[4][2], al[4][2];
#pragma unroll
    for (int i = 0; i < 4; ++i)
#pragma unroll
        for (int s = 0; s < 2; ++s) {
            const float* xp = x + (size_t)(r0w + 16 * i + l15) * DIM + 32 * s + 8 * quad;
            float4 f0 = *(const float4*)xp;
            float4 f1 = *(const float4*)(xp + 4);
            float w[8] = {f0.x, f0.y, f0.z, f0.w, f1.x, f1.y, f1.z, f1.w};
            short8 h, l;
#pragma unroll
            for (int j = 0; j < 8; ++j) {
                unsigned short hb = bf16rn(w[j]);
                float hf = __uint_as_float(((unsigned int)hb) << 16);
                h[j] = (short)hb;
                l[j] = (short)bf16rn(w[j] - hf);
            }
            ah[i][s] = h;
            al[i][s] = l;
        }

    // per-lane swizzled LDS frag bases (shorts): row=16j+l15, k-window w, granule
    // phys = j*2048B + l15*128B + (((w<<2)|quad) ^ (l15&7))<<4 ; lo half = +8192B
    const int fld = quad ^ (l15 & 7);
    const unsigned short* eb = &ebuf[0][0];
    const unsigned short* va0 = eb + ((l15 * 128 + (fld << 4)) >> 1);
    const unsigned short* va1 = eb + ((l15 * 128 + ((fld ^ 4) << 4)) >> 1);

    float s1[16], s2[16];
    int c1[16];
#pragma unroll
    for (int t = 0; t < 16; ++t) { s1[t] = -3.4e38f; s2[t] = -3.4e38f; c1[t] = 0; }

    __syncthreads();   // chunk 0 landed (drains vmcnt), e2l ready

    int cur = 0;
    for (int ch = 0; ch < NCH; ++ch) {
        STAGE((ch + 1) & (NCH - 1), cur ^ 1);   // prefetch next (wraps harmlessly)

        const int c0 = ch * CK;
        const unsigned short* p0 = va0 + cur * 8192;
        const unsigned short* p1 = va1 + cur * 8192;

        f32x4 acc[4][4];
#pragma unroll
        for (int j = 0; j < 4; ++j) {
            const float ev = -0.5f * e2l[c0 + 16 * j + l15];
            const f32x4 iv = {ev, ev, ev, ev};
#pragma unroll
            for (int i = 0; i < 4; ++i) acc[i][j] = iv;
        }

#pragma unroll
        for (int j = 0; j < 4; ++j) {
            short8 bh0 = *(const short8*)(p0 + j * 1024);
            short8 bh1 = *(const short8*)(p1 + j * 1024);
            short8 bl0 = *(const short8*)(p0 + j * 1024 + 4096);
            short8 bl1 = *(const short8*)(p1 + j * 1024 + 4096);
#pragma unroll
            for (int i = 0; i < 4; ++i) {
                f32x4 a = acc[i][j];
                a = __builtin_amdgcn_mfma_f32_16x16x32_bf16(ah[i][0], bh0, a, 0, 0, 0);
                a = __builtin_amdgcn_mfma_f32_16x16x32_bf16(ah[i][1], bh1, a, 0, 0, 0);
                a = __builtin_amdgcn_mfma_f32_16x16x32_bf16(ah[i][0], bl0, a, 0, 0, 0);
                a = __builtin_amdgcn_mfma_f32_16x16x32_bf16(ah[i][1], bl1, a, 0, 0, 0);
                a = __builtin_amdgcn_mfma_f32_16x16x32_bf16(al[i][0], bh0, a, 0, 0, 0);
                a = __builtin_amdgcn_mfma_f32_16x16x32_bf16(al[i][1], bh1, a, 0, 0, 0);
                acc[i][j] = a;
            }
        }

        // epilogue: C/D layout col=l15, row=quad*4+r (per 16-tile i); argmax d
#pragma unroll
        for (int j = 0; j < 4; ++j) {
            const int c = c0 + 16 * j + l15;
#pragma unroll
            for (int i = 0; i < 4; ++i)
#pragma unroll
                for (int r = 0; r < 4; ++r) {
                    float d = acc[i][j][r];
                    const int st = i * 4 + r;
                    bool gt = d > s1[st];
                    // running second-max: med3(d, s1_old, s2_old)
                    float ns2;
                    asm("v_med3_f32 %0, %1, %2, %3"
                        : "=v"(ns2) : "v"(d), "v"(s1[st]), "v"(s2[st]));
                    s2[st] = ns2;
                    c1[st] = gt ? c : c1[st];
                    s1[st] = fmaxf(s1[st], d);
                }
        }

        __syncthreads();   // next-chunk DMA landed; all waves done reading cur
        cur ^= 1;
    }

    // butterfly top-2 merge across the 16 lanes (same quad) sharing each row
#pragma unroll
    for (int st = 0; st < 16; ++st) {
#pragma unroll
        for (int m = 1; m < 16; m <<= 1) {
            float os1 = __shfl_xor(s1[st], m, 64);
            float os2 = __shfl_xor(s2[st], m, 64);
            int   oc1 = __shfl_xor(c1[st], m, 64);
            bool take = (os1 > s1[st]) || (os1 == s1[st] && oc1 < c1[st]);
            float loser = take ? s1[st] : os1;
            s2[st] = fmaxf(fmaxf(s2[st], os2), loser);
            if (take) { s1[st] = os1; c1[st] = oc1; }
        }
    }
    if (l15 == 0) {
#pragma unroll
        for (int st = 0; st < 16; ++st) {
            const int i = st >> 2, r = st & 3;
            const int row = r0w + 16 * i + 4 * quad + r;
            ind_ws[row] = c1[st];
            ind_out[row] = (float)c1[st];
            if (s1[st] - s2[st] < HEPS) {    // score gap = 2*(s1-s2) < EPS
                int p = atomicAdd(cnt, 1);
                list[p] = row;
            }
        }
    }
#undef STAGE
}

// ---- exact fp32 re-solve for flagged rows (block per row, round-0 structure) ----
// No register blocking: RB>1 spilled twice (r1: 817MB, r2: 88MB scratch writes).
// #pragma unroll 4 keeps only 4 float4 in flight -> ~24 live VGPRs, spill-free.
__global__ __launch_bounds__(256, 2) void refine_kernel(
        const float* __restrict__ x,
        const float* __restrict__ embed,
        const float* __restrict__ e2g,
        const int* __restrict__ cnt,
        const int* __restrict__ list,
        int* __restrict__ ind_ws,
        float* __restrict__ ind_out) {
    __shared__ float xr[DIM];
    __shared__ unsigned long long red[256];
    const int tid = threadIdx.x;
    const int n = *cnt;
    for (int f = blockIdx.x; f < n; f += gridDim.x) {
        const int row = list[f];
        __syncthreads();
        if (tid < 16)
            ((float4*)xr)[tid] = ((const float4*)(x + (size_t)row * DIM))[tid];
        __syncthreads();
        unsigned long long best = ~0ull;
        for (int c = tid; c < K_CODES; c += 256) {
            const float4* ep = (const float4*)(embed + (size_t)c * DIM);
            float d0 = 0.f, d1 = 0.f, d2 = 0.f, d3 = 0.f;
#pragma unroll 4
            for (int q = 0; q < 16; ++q) {
                float4 ev = ep[q];
                d0 = fmaf(xr[4 * q + 0], ev.x, d0);
                d1 = fmaf(xr[4 * q + 1], ev.y, d1);
                d2 = fmaf(xr[4 * q + 2], ev.z, d2);
                d3 = fmaf(xr[4 * q + 3], ev.w, d3);
            }
            float sc = fmaf(-2.f, (d0 + d1) + (d2 + d3), e2g[c]);
            unsigned long long key =
                ((unsigned long long)fkey(sc) << 32) | (unsigned int)c;
            if (key < best) best = key;
        }
        red[tid] = best;
        __syncthreads();
        for (int w = 128; w > 0; w >>= 1) {
            if (tid < w && red[tid + w] < red[tid]) red[tid] = red[tid + w];
            __syncthreads();
        }
        if (tid == 0) {
            int k = (int)(red[0] & 0xFFFFFFFFull);
            ind_ws[row] = k;
            ind_out[row] = (float)k;
        }
    }
}

// ---- gather quantize + scatter stats (one wave = one row) ----
__global__ void scatter_kernel(const float* __restrict__ x,
                               const float* __restrict__ embed,
                               const int* __restrict__ ind,
                               float* __restrict__ quant,
                               float* __restrict__ cs,
                               float* __restrict__ esum) {
    const int t = blockIdx.x * blockDim.x + threadIdx.x;
    const int row = t >> 6;
    const int d = t & 63;
    const int k = ind[row];
    quant[t] = embed[(size_t)k * DIM + d];
    atomicAdd(&esum[(size_t)k * DIM + d], x[t]);
    if (d == 0) atomicAdd(&cs[k], 1.0f);
}

extern "C" void kernel_launch(void* const* d_in, const int* in_sizes, int n_in,
                              void* d_out, int out_size, void* d_ws, size_t ws_size,
                              hipStream_t stream) {
    const float* x     = (const float*)d_in[0];
    const float* embed = (const float*)d_in[1];

    float* out     = (float*)d_out;
    float* quant   = out;                            // [N, D]
    float* ind_out = out + (size_t)N_ROWS * DIM;     // [N] (as float)
    float* cs      = ind_out + N_ROWS;               // [K]
    float* esum    = cs + K_CODES;                   // [K, D]

    // ws: e2 [K] | cnt [4 ints] | list [N] | ind_ws [N]   (~1.1 MB, unchanged)
    float* e2   = (float*)d_ws;
    int* cnt    = (int*)(e2 + K_CODES);
    int* list   = cnt + 4;
    int* ind_ws = list + N_ROWS;

    // bf16 hi/lo packed embed images live in the quant region of d_out (1 MB);
    // nothing reads them after dist, and scatter fully overwrites quant later.
    unsigned short* ebf = (unsigned short*)quant;

    hipMemsetAsync(cs, 0, (size_t)(K_CODES + K_CODES * DIM) * sizeof(float), stream);
    hipMemsetAsync(cnt, 0, sizeof(int), stream);

    e2_kernel<<<K_CODES / 256, 256, 0, stream>>>(embed, e2);
    pack_kernel<<<(NCH * 16384 / 16) / 256, 256, 0, stream>>>(embed, ebf);
    dist_argmin_kernel<<<N_ROWS / BROWS, 256, 0, stream>>>(
        x, ebf, e2, ind_ws, ind_out, cnt, list);
    refine_kernel<<<1024, 256, 0, stream>>>(x, embed, e2, cnt, list, ind_ws, ind_out);
    scatter_kernel<<<(size_t)N_ROWS * DIM / 256, 256, 0, stream>>>(
        x, embed, ind_ws, quant, cs, esum);
}

// Round 4
// 451.680 us; speedup vs baseline: 4.5390x; 4.5390x over previous
//
#include <hip/hip_runtime.h>

#define N_ROWS 131072
#define DIM 64
#define K_CODES 4096
#define BROWS 256            // rows per block = 4 waves x 64
#define CK 64                // cols per chunk
#define NCH (K_CODES / CK)   // 64 chunks
#define EST 72               // LDS bf16 stride (64 + 8 pad) -> bank-balanced frags
#define EPS 0.015625f        // flag margin: >=15x the bf16x3 numeric error bound

typedef __attribute__((ext_vector_type(8))) short short8;
typedef __attribute__((ext_vector_type(4))) float f32x4;

__device__ inline unsigned short bf16rn(float f) {      // round-nearest-even
    unsigned int u = __float_as_uint(f);
    u += 0x7FFFu + ((u >> 16) & 1u);
    return (unsigned short)(u >> 16);
}
// order-preserving float -> uint32 (finite scores)
__device__ inline unsigned int fkey(float f) {
    unsigned int u = __float_as_uint(f);
    return (u & 0x80000000u) ? ~u : (u | 0x80000000u);
}

// ---- e2[k] = sum_d embed[k][d]^2 (exact fp32) ----
__global__ void e2_kernel(const float* __restrict__ embed, float* __restrict__ e2) {
    int k = blockIdx.x * blockDim.x + threadIdx.x;
    const float4* e = reinterpret_cast<const float4*>(embed + (size_t)k * DIM);
    float s = 0.f;
#pragma unroll
    for (int i = 0; i < DIM / 4; ++i) {
        float4 v = e[i];
        s = fmaf(v.x, v.x, s);
        s = fmaf(v.y, v.y, s);
        s = fmaf(v.z, v.z, s);
        s = fmaf(v.w, v.w, s);
    }
    e2[k] = s;
}

// ---- pack embed -> bf16 hi/lo, layout [code][hi 64 bf16 | lo 64 bf16] ----
// Plain row-major, no swizzle. Replaces the per-block fp32->bf16 re-conversion
// that rounds-0's dist did 512x (the dominant VALU cost identified in r0 PMC).
// NOTE: rounds 1-3's swizzled-image + d-space-argmax dist rewrite inflated the
// ambiguity-flag count ~100x (refine became L2-BW-bound: 810-1770us). Root line
// not identified by inspection -> that rewrite is fully reverted; this pack
// keeps LDS contents BIT-IDENTICAL to the proven round-0 kernel.
__global__ void pack_kernel(const float* __restrict__ embed,
                            unsigned short* __restrict__ ebf) {
    const int g = blockIdx.x * blockDim.x + threadIdx.x;   // granule id (8 bf16)
    const int code = g >> 4;                               // 16 granules / code
    const int w    = g & 15;
    const int half = w >> 3;                               // 0 = hi, 1 = lo
    const int d0   = (w & 7) << 3;                         // dim 0..56
    const float* ep = embed + (size_t)code * DIM + d0;
    float4 f0 = *(const float4*)ep;
    float4 f1 = *(const float4*)(ep + 4);
    float wv[8] = {f0.x, f0.y, f0.z, f0.w, f1.x, f1.y, f1.z, f1.w};
    unsigned short o[8];
#pragma unroll
    for (int j = 0; j < 8; ++j) {
        unsigned short hb = bf16rn(wv[j]);
        if (half == 0) {
            o[j] = hb;
        } else {
            float hf = __uint_as_float(((unsigned int)hb) << 16);
            o[j] = bf16rn(wv[j] - hf);
        }
    }
    *(uint4*)(ebf + (size_t)code * 128 + half * 64 + d0) = *(uint4*)o;
}

// ---- MFMA distance + fused top-2 argmin (round-0 proven structure) ----
// Wave = 64 rows, A (xh,xl frags) in registers for the whole sweep.
// acc = xh*eh + xh*el + xl*eh (bf16x3), score = e2 - 2*acc.
__global__ __launch_bounds__(256, 2) void dist_argmin_kernel(
        const float* __restrict__ x, const unsigned short* __restrict__ ebf,
        const float* __restrict__ e2g, int* __restrict__ ind_ws,
        float* __restrict__ ind_out, int* __restrict__ cnt,
        int* __restrict__ list) {
    __shared__ unsigned short esh[CK * EST];   // 9216 B
    __shared__ unsigned short esl[CK * EST];   // 9216 B
    __shared__ float e2s[CK];

    const int tid  = threadIdx.x;
    const int l15  = tid & 15;
    const int quad = (tid >> 4) & 3;
    const int wave = tid >> 6;
    const int r0w  = blockIdx.x * BROWS + wave * 64;

    // A-frags: A[m=l15][k=quad*8+j] per 16x16x32; rows 16i+l15, k-windows 32s+8q
    short8 ah[4][2], al[4][2];
#pragma unroll
    for (int i = 0; i < 4; ++i)
#pragma unroll
        for (int s = 0; s < 2; ++s) {
            const float* xp = x + (size_t)(r0w + 16 * i + l15) * DIM + 32 * s + 8 * quad;
            float4 f0 = *(const float4*)xp;
            float4 f1 = *(const float4*)(xp + 4);
            float w[8] = {f0.x, f0.y, f0.z, f0.w, f1.x, f1.y, f1.z, f1.w};
            short8 h, l;
#pragma unroll
            for (int j = 0; j < 8; ++j) {
                unsigned short hb = bf16rn(w[j]);
                float hf = __uint_as_float(((unsigned int)hb) << 16);
                h[j] = (short)hb;
                l[j] = (short)bf16rn(w[j] - hf);
            }
            ah[i][s] = h;
            al[i][s] = l;
        }

    float s1[16], s2[16];
    int c1[16];
#pragma unroll
    for (int t = 0; t < 16; ++t) { s1[t] = 3.4e38f; s2[t] = 3.4e38f; c1[t] = 0; }

    for (int ch = 0; ch < NCH; ++ch) {
        const int c0 = ch * CK;
        __syncthreads();   // prior chunk's frag reads done
        {   // stage pre-packed bf16 hi/lo (pure copy, zero conversion VALU)
            const int col = tid >> 2;
            const int dq  = (tid & 3) * 16;
            const unsigned short* pp = ebf + (size_t)(c0 + col) * 128 + dq;
            uint4 h0 = *(const uint4*)pp;          // dims dq..dq+8   (hi)
            uint4 h1 = *(const uint4*)(pp + 8);    // dims dq+8..dq+16 (hi)
            uint4 l0 = *(const uint4*)(pp + 64);   // (lo)
            uint4 l1 = *(const uint4*)(pp + 72);
            *(uint4*)(&esh[col * EST + dq])     = h0;
            *(uint4*)(&esh[col * EST + dq + 8]) = h1;
            *(uint4*)(&esl[col * EST + dq])     = l0;
            *(uint4*)(&esl[col * EST + dq + 8]) = l1;
            if (tid < CK) e2s[tid] = e2g[c0 + tid];
        }
        __syncthreads();   // es ready

        f32x4 acc[4][4];
#pragma unroll
        for (int i = 0; i < 4; ++i)
#pragma unroll
            for (int j = 0; j < 4; ++j) acc[i][j] = (f32x4){0.f, 0.f, 0.f, 0.f};

#pragma unroll
        for (int j = 0; j < 4; ++j) {
            const int cb = (16 * j + l15) * EST + 8 * quad;   // B[n=l15][k=8q+j]
            short8 bh0 = *(const short8*)(&esh[cb]);
            short8 bh1 = *(const short8*)(&esh[cb + 32]);
            short8 bl0 = *(const short8*)(&esl[cb]);
            short8 bl1 = *(const short8*)(&esl[cb + 32]);
#pragma unroll
            for (int i = 0; i < 4; ++i) {
                f32x4 a = acc[i][j];
                a = __builtin_amdgcn_mfma_f32_16x16x32_bf16(ah[i][0], bh0, a, 0, 0, 0);
                a = __builtin_amdgcn_mfma_f32_16x16x32_bf16(ah[i][1], bh1, a, 0, 0, 0);
                a = __builtin_amdgcn_mfma_f32_16x16x32_bf16(ah[i][0], bl0, a, 0, 0, 0);
                a = __builtin_amdgcn_mfma_f32_16x16x32_bf16(ah[i][1], bl1, a, 0, 0, 0);
                a = __builtin_amdgcn_mfma_f32_16x16x32_bf16(al[i][0], bh0, a, 0, 0, 0);
                a = __builtin_amdgcn_mfma_f32_16x16x32_bf16(al[i][1], bh1, a, 0, 0, 0);
                acc[i][j] = a;
            }
        }

        // epilogue: C/D layout col=l15, row=quad*4+r (per 16-tile i)
#pragma unroll
        for (int j = 0; j < 4; ++j) {
            const int c = c0 + 16 * j + l15;
            const float e2v = e2s[16 * j + l15];
#pragma unroll
            for (int i = 0; i < 4; ++i)
#pragma unroll
                for (int r = 0; r < 4; ++r) {
                    float sc = fmaf(-2.f, acc[i][j][r], e2v);
                    const int st = i * 4 + r;
                    bool lt = sc < s1[st];
                    s2[st] = lt ? s1[st] : fminf(s2[st], sc);
                    c1[st] = lt ? c : c1[st];
                    s1[st] = lt ? sc : s1[st];
                }
        }
    }

    // butterfly top-2 merge across the 16 lanes (same quad) sharing each row
#pragma unroll
    for (int st = 0; st < 16; ++st) {
#pragma unroll
        for (int m = 1; m < 16; m <<= 1) {
            float os1 = __shfl_xor(s1[st], m, 64);
            float os2 = __shfl_xor(s2[st], m, 64);
            int   oc1 = __shfl_xor(c1[st], m, 64);
            bool take = (os1 < s1[st]) || (os1 == s1[st] && oc1 < c1[st]);
            float loser = take ? s1[st] : os1;
            s2[st] = fminf(fminf(s2[st], os2), loser);
            if (take) { s1[st] = os1; c1[st] = oc1; }
        }
    }
    if (l15 == 0) {
#pragma unroll
        for (int st = 0; st < 16; ++st) {
            const int i = st >> 2, r = st & 3;
            const int row = r0w + 16 * i + 4 * quad + r;
            ind_ws[row] = c1[st];
            ind_out[row] = (float)c1[st];
            if (s2[st] - s1[st] < EPS) {     // ambiguous under bf16x3 error
                int p = atomicAdd(cnt, 1);
                list[p] = row;
            }
        }
    }
}

// ---- exact fp32 re-solve for flagged rows (block per row, round-0 proven) ----
// Full unroll (16 float4 in flight) + no launch_bounds: the compiler picks a
// spill-free VGPR budget (r1/r2 showed any forced cap or RB-blocking spills).
__global__ void refine_kernel(const float* __restrict__ x,
                              const float* __restrict__ embed,
                              const float* __restrict__ e2g,
                              const int* __restrict__ cnt,
                              const int* __restrict__ list,
                              int* __restrict__ ind_ws,
                              float* __restrict__ ind_out) {
    __shared__ float xr[DIM];
    __shared__ unsigned long long red[256];
    const int tid = threadIdx.x;
    const int n = *cnt;
    for (int f = blockIdx.x; f < n; f += gridDim.x) {
        const int row = list[f];
        __syncthreads();
        if (tid < 16)
            ((float4*)xr)[tid] = ((const float4*)(x + (size_t)row * DIM))[tid];
        __syncthreads();
        unsigned long long best = ~0ull;
        for (int c = tid; c < K_CODES; c += 256) {
            const float4* ep = (const float4*)(embed + (size_t)c * DIM);
            float d0 = 0.f, d1 = 0.f, d2 = 0.f, d3 = 0.f;
#pragma unroll
            for (int q = 0; q < 16; ++q) {
                float4 ev = ep[q];
                d0 = fmaf(xr[4 * q + 0], ev.x, d0);
                d1 = fmaf(xr[4 * q + 1], ev.y, d1);
                d2 = fmaf(xr[4 * q + 2], ev.z, d2);
                d3 = fmaf(xr[4 * q + 3], ev.w, d3);
            }
            float sc = fmaf(-2.f, (d0 + d1) + (d2 + d3), e2g[c]);
            unsigned long long key =
                ((unsigned long long)fkey(sc) << 32) | (unsigned int)c;
            if (key < best) best = key;
        }
        red[tid] = best;
        __syncthreads();
        for (int w = 128; w > 0; w >>= 1) {
            if (tid < w && red[tid + w] < red[tid]) red[tid] = red[tid + w];
            __syncthreads();
        }
        if (tid == 0) {
            int k = (int)(red[0] & 0xFFFFFFFFull);
            ind_ws[row] = k;
            ind_out[row] = (float)k;
        }
    }
}

// ---- gather quantize + scatter stats (one wave = one row) ----
__global__ void scatter_kernel(const float* __restrict__ x,
                               const float* __restrict__ embed,
                               const int* __restrict__ ind,
                               float* __restrict__ quant,
                               float* __restrict__ cs,
                               float* __restrict__ esum) {
    const int t = blockIdx.x * blockDim.x + threadIdx.x;
    const int row = t >> 6;
    const int d = t & 63;
    const int k = ind[row];
    quant[t] = embed[(size_t)k * DIM + d];
    atomicAdd(&esum[(size_t)k * DIM + d], x[t]);
    if (d == 0) atomicAdd(&cs[k], 1.0f);
}

extern "C" void kernel_launch(void* const* d_in, const int* in_sizes, int n_in,
                              void* d_out, int out_size, void* d_ws, size_t ws_size,
                              hipStream_t stream) {
    const float* x     = (const float*)d_in[0];
    const float* embed = (const float*)d_in[1];

    float* out     = (float*)d_out;
    float* quant   = out;                            // [N, D]
    float* ind_out = out + (size_t)N_ROWS * DIM;     // [N] (as float)
    float* cs      = ind_out + N_ROWS;               // [K]
    float* esum    = cs + K_CODES;                   // [K, D]

    // ws: e2 [K] | cnt [4 ints] | list [N] | ind_ws [N]   (~1.1 MB)
    float* e2   = (float*)d_ws;
    int* cnt    = (int*)(e2 + K_CODES);
    int* list   = cnt + 4;
    int* ind_ws = list + N_ROWS;

    // bf16 hi/lo packed embed lives in the quant region of d_out (1 MB);
    // nothing reads it after dist, and scatter fully overwrites quant later.
    unsigned short* ebf = (unsigned short*)quant;

    hipMemsetAsync(cs, 0, (size_t)(K_CODES + K_CODES * DIM) * sizeof(float), stream);
    hipMemsetAsync(cnt, 0, sizeof(int), stream);

    e2_kernel<<<K_CODES / 256, 256, 0, stream>>>(embed, e2);
    pack_kernel<<<(K_CODES * 16) / 256, 256, 0, stream>>>(embed, ebf);
    dist_argmin_kernel<<<N_ROWS / BROWS, 256, 0, stream>>>(
        x, ebf, e2, ind_ws, ind_out, cnt, list);
    refine_kernel<<<512, 256, 0, stream>>>(x, embed, e2, cnt, list, ind_ws, ind_out);
    scatter_kernel<<<(size_t)N_ROWS * DIM / 256, 256, 0, stream>>>(
        x, embed, ind_ws, quant, cs, esum);
}

// Round 5
// 443.321 us; speedup vs baseline: 4.6246x; 1.0189x over previous
//
#include <hip/hip_runtime.h>

#define N_ROWS 131072
#define DIM 64
#define K_CODES 4096
#define BROWS 256            // rows per block = 4 waves x 64
#define CK 64                // cols per chunk
#define NCH (K_CODES / CK)   // 64 chunks
#define EST 72               // LDS bf16 stride (64 + 8 pad) -> bank-balanced frags
#define EPS 0.015625f        // flag margin in score space (>=15x bf16x3 error bound)
#define HEPS 0.0078125f      // EPS/2 in d-space (score = -2*d + const)

typedef __attribute__((ext_vector_type(8))) short short8;
typedef __attribute__((ext_vector_type(4))) float f32x4;

__device__ inline unsigned short bf16rn(float f) {      // round-nearest-even
    unsigned int u = __float_as_uint(f);
    u += 0x7FFFu + ((u >> 16) & 1u);
    return (unsigned short)(u >> 16);
}
// order-preserving float -> uint32 (finite scores)
__device__ inline unsigned int fkey(float f) {
    unsigned int u = __float_as_uint(f);
    return (u & 0x80000000u) ? ~u : (u | 0x80000000u);
}

// ---- pack embed -> bf16 hi/lo [code][hi 64 | lo 64], plus e2 / -e2/2, plus
//      zero-fill of cnt and the cs/esum output stats (replaces 2 memsets and
//      the separate e2 kernel: 7 dispatches -> 4).
// Plain row-major, no swizzle: LDS contents in dist stay BIT-IDENTICAL to the
// proven round-0/round-4 kernel (rounds 1-3's swizzled staging inflated the
// ambiguity-flag count ~100x; that path stays dead).
__global__ void pack_kernel(const float* __restrict__ embed,
                            unsigned short* __restrict__ ebf,
                            float* __restrict__ e2,       // exact, for refine
                            float* __restrict__ e2h,      // -e2/2, for dist init
                            int* __restrict__ cnt,
                            float* __restrict__ cs) {     // cs..esum contiguous
    const int g = blockIdx.x * blockDim.x + threadIdx.x;   // K*16 = 65536 thr
    // zero stats: cs [K] followed contiguously by esum [K*D]
    for (int i = g; i < K_CODES + K_CODES * DIM; i += K_CODES * 16)
        cs[i] = 0.f;
    if (g == 0) *cnt = 0;

    const int code = g >> 4;                               // 16 granules / code
    const int w    = g & 15;
    const int half = w >> 3;                               // 0 = hi, 1 = lo
    const int d0   = (w & 7) << 3;                         // dim 0..56
    const float* ep = embed + (size_t)code * DIM + d0;
    float4 f0 = *(const float4*)ep;
    float4 f1 = *(const float4*)(ep + 4);
    float wv[8] = {f0.x, f0.y, f0.z, f0.w, f1.x, f1.y, f1.z, f1.w};
    unsigned short o[8];
    float ssq = 0.f;
#pragma unroll
    for (int j = 0; j < 8; ++j) {
        unsigned short hb = bf16rn(wv[j]);
        if (half == 0) {
            o[j] = hb;
            ssq = fmaf(wv[j], wv[j], ssq);
        } else {
            float hf = __uint_as_float(((unsigned int)hb) << 16);
            o[j] = bf16rn(wv[j] - hf);
        }
    }
    *(uint4*)(ebf + (size_t)code * 128 + half * 64 + d0) = *(uint4*)o;
    // e2: reduce ssq across the 8 hi-granule lanes of this code (lanes are
    // contiguous: lane = code*16 + w within the wave; masks 1/2/4 stay inside)
    ssq += __shfl_xor(ssq, 1, 64);
    ssq += __shfl_xor(ssq, 2, 64);
    ssq += __shfl_xor(ssq, 4, 64);
    if (w == 0) {
        e2[code]  = ssq;
        e2h[code] = -0.5f * ssq;
    }
}

// ---- MFMA distance + fused top-2 argmax(d), d = x.e - e2/2 ----
// Staging path identical to round-4 (proven). Epilogue changes only:
// acc init = -e2/2 (e2-fold: kills 64 fmaf/chunk), argmax-d tracking with
// clamp-idiom second-max (med3-fusable). Flag gap in d-space: HEPS = EPS/2.
__global__ __launch_bounds__(256, 2) void dist_argmin_kernel(
        const float* __restrict__ x, const unsigned short* __restrict__ ebf,
        const float* __restrict__ e2h, int* __restrict__ ind_ws,
        float* __restrict__ ind_out, int* __restrict__ cnt,
        int* __restrict__ list) {
    __shared__ unsigned short esh[CK * EST];   // 9216 B
    __shared__ unsigned short esl[CK * EST];   // 9216 B
    __shared__ float e2s[CK];                  // holds -e2/2

    const int tid  = threadIdx.x;
    const int l15  = tid & 15;
    const int quad = (tid >> 4) & 3;
    const int wave = tid >> 6;
    const int r0w  = blockIdx.x * BROWS + wave * 64;

    // A-frags: A[m=l15][k=quad*8+j] per 16x16x32; rows 16i+l15, k-windows 32s+8q
    short8 ah[4][2], al[4][2];
#pragma unroll
    for (int i = 0; i < 4; ++i)
#pragma unroll
        for (int s = 0; s < 2; ++s) {
            const float* xp = x + (size_t)(r0w + 16 * i + l15) * DIM + 32 * s + 8 * quad;
            float4 f0 = *(const float4*)xp;
            float4 f1 = *(const float4*)(xp + 4);
            float w[8] = {f0.x, f0.y, f0.z, f0.w, f1.x, f1.y, f1.z, f1.w};
            short8 h, l;
#pragma unroll
            for (int j = 0; j < 8; ++j) {
                unsigned short hb = bf16rn(w[j]);
                float hf = __uint_as_float(((unsigned int)hb) << 16);
                h[j] = (short)hb;
                l[j] = (short)bf16rn(w[j] - hf);
            }
            ah[i][s] = h;
            al[i][s] = l;
        }

    float s1[16], s2[16];
    int c1[16];
#pragma unroll
    for (int t = 0; t < 16; ++t) { s1[t] = -3.4e38f; s2[t] = -3.4e38f; c1[t] = 0; }

    for (int ch = 0; ch < NCH; ++ch) {
        const int c0 = ch * CK;
        __syncthreads();   // prior chunk's frag reads done
        {   // stage pre-packed bf16 hi/lo (pure copy, zero conversion VALU)
            const int col = tid >> 2;
            const int dq  = (tid & 3) * 16;
            const unsigned short* pp = ebf + (size_t)(c0 + col) * 128 + dq;
            uint4 h0 = *(const uint4*)pp;          // dims dq..dq+8   (hi)
            uint4 h1 = *(const uint4*)(pp + 8);    // dims dq+8..dq+16 (hi)
            uint4 l0 = *(const uint4*)(pp + 64);   // (lo)
            uint4 l1 = *(const uint4*)(pp + 72);
            *(uint4*)(&esh[col * EST + dq])     = h0;
            *(uint4*)(&esh[col * EST + dq + 8]) = h1;
            *(uint4*)(&esl[col * EST + dq])     = l0;
            *(uint4*)(&esl[col * EST + dq + 8]) = l1;
            if (tid < CK) e2s[tid] = e2h[c0 + tid];
        }
        __syncthreads();   // es ready

        // acc init = -e2[col]/2 (C/D col = l15 per 16-tile j)
        f32x4 acc[4][4];
#pragma unroll
        for (int j = 0; j < 4; ++j) {
            const float ev = e2s[16 * j + l15];
            const f32x4 iv = {ev, ev, ev, ev};
#pragma unroll
            for (int i = 0; i < 4; ++i) acc[i][j] = iv;
        }

#pragma unroll
        for (int j = 0; j < 4; ++j) {
            const int cb = (16 * j + l15) * EST + 8 * quad;   // B[n=l15][k=8q+j]
            short8 bh0 = *(const short8*)(&esh[cb]);
            short8 bh1 = *(const short8*)(&esh[cb + 32]);
            short8 bl0 = *(const short8*)(&esl[cb]);
            short8 bl1 = *(const short8*)(&esl[cb + 32]);
#pragma unroll
            for (int i = 0; i < 4; ++i) {
                f32x4 a = acc[i][j];
                a = __builtin_amdgcn_mfma_f32_16x16x32_bf16(ah[i][0], bh0, a, 0, 0, 0);
                a = __builtin_amdgcn_mfma_f32_16x16x32_bf16(ah[i][1], bh1, a, 0, 0, 0);
                a = __builtin_amdgcn_mfma_f32_16x16x32_bf16(ah[i][0], bl0, a, 0, 0, 0);
                a = __builtin_amdgcn_mfma_f32_16x16x32_bf16(ah[i][1], bl1, a, 0, 0, 0);
                a = __builtin_amdgcn_mfma_f32_16x16x32_bf16(al[i][0], bh0, a, 0, 0, 0);
                a = __builtin_amdgcn_mfma_f32_16x16x32_bf16(al[i][1], bh1, a, 0, 0, 0);
                acc[i][j] = a;
            }
        }

        // epilogue: C/D layout col=l15, row=quad*4+r (per 16-tile i); argmax d.
        // second-max via clamp idiom: s2' = max(min(d, s1), s2)  (== med3)
#pragma unroll
        for (int j = 0; j < 4; ++j) {
            const int c = c0 + 16 * j + l15;
#pragma unroll
            for (int i = 0; i < 4; ++i)
#pragma unroll
                for (int r = 0; r < 4; ++r) {
                    float d = acc[i][j][r];
                    const int st = i * 4 + r;
                    bool gt = d > s1[st];
                    s2[st] = fmaxf(fminf(d, s1[st]), s2[st]);
                    c1[st] = gt ? c : c1[st];
                    s1[st] = fmaxf(s1[st], d);
                }
        }
    }

    // butterfly top-2 merge across the 16 lanes (same quad) sharing each row
#pragma unroll
    for (int st = 0; st < 16; ++st) {
#pragma unroll
        for (int m = 1; m < 16; m <<= 1) {
            float os1 = __shfl_xor(s1[st], m, 64);
            float os2 = __shfl_xor(s2[st], m, 64);
            int   oc1 = __shfl_xor(c1[st], m, 64);
            bool take = (os1 > s1[st]) || (os1 == s1[st] && oc1 < c1[st]);
            float loser = take ? s1[st] : os1;
            s2[st] = fmaxf(fmaxf(s2[st], os2), loser);
            if (take) { s1[st] = os1; c1[st] = oc1; }
        }
    }
    if (l15 == 0) {
#pragma unroll
        for (int st = 0; st < 16; ++st) {
            const int i = st >> 2, r = st & 3;
            const int row = r0w + 16 * i + 4 * quad + r;
            ind_ws[row] = c1[st];
            ind_out[row] = (float)c1[st];
            if (s1[st] - s2[st] < HEPS) {    // d-gap = score-gap/2 < EPS/2
                int p = atomicAdd(cnt, 1);
                list[p] = row;
            }
        }
    }
}

// ---- exact fp32 re-solve for flagged rows (block per row, round-0 proven) ----
// Full unroll (16 float4 in flight) + no launch_bounds: the compiler picks a
// spill-free VGPR budget (r1/r2 showed any forced cap or RB-blocking spills).
__global__ void refine_kernel(const float* __restrict__ x,
                              const float* __restrict__ embed,
                              const float* __restrict__ e2g,
                              const int* __restrict__ cnt,
                              const int* __restrict__ list,
                              int* __restrict__ ind_ws,
                              float* __restrict__ ind_out) {
    __shared__ float xr[DIM];
    __shared__ unsigned long long red[256];
    const int tid = threadIdx.x;
    const int n = *cnt;
    for (int f = blockIdx.x; f < n; f += gridDim.x) {
        const int row = list[f];
        __syncthreads();
        if (tid < 16)
            ((float4*)xr)[tid] = ((const float4*)(x + (size_t)row * DIM))[tid];
        __syncthreads();
        unsigned long long best = ~0ull;
        for (int c = tid; c < K_CODES; c += 256) {
            const float4* ep = (const float4*)(embed + (size_t)c * DIM);
            float d0 = 0.f, d1 = 0.f, d2 = 0.f, d3 = 0.f;
#pragma unroll
            for (int q = 0; q < 16; ++q) {
                float4 ev = ep[q];
                d0 = fmaf(xr[4 * q + 0], ev.x, d0);
                d1 = fmaf(xr[4 * q + 1], ev.y, d1);
                d2 = fmaf(xr[4 * q + 2], ev.z, d2);
                d3 = fmaf(xr[4 * q + 3], ev.w, d3);
            }
            float sc = fmaf(-2.f, (d0 + d1) + (d2 + d3), e2g[c]);
            unsigned long long key =
                ((unsigned long long)fkey(sc) << 32) | (unsigned int)c;
            if (key < best) best = key;
        }
        red[tid] = best;
        __syncthreads();
        for (int w = 128; w > 0; w >>= 1) {
            if (tid < w && red[tid + w] < red[tid]) red[tid] = red[tid + w];
            __syncthreads();
        }
        if (tid == 0) {
            int k = (int)(red[0] & 0xFFFFFFFFull);
            ind_ws[row] = k;
            ind_out[row] = (float)k;
        }
    }
}

// ---- gather quantize + scatter stats (one wave = one row) ----
__global__ void scatter_kernel(const float* __restrict__ x,
                               const float* __restrict__ embed,
                               const int* __restrict__ ind,
                               float* __restrict__ quant,
                               float* __restrict__ cs,
                               float* __restrict__ esum) {
    const int t = blockIdx.x * blockDim.x + threadIdx.x;
    const int row = t >> 6;
    const int d = t & 63;
    const int k = ind[row];
    quant[t] = embed[(size_t)k * DIM + d];
    atomicAdd(&esum[(size_t)k * DIM + d], x[t]);
    if (d == 0) atomicAdd(&cs[k], 1.0f);
}

extern "C" void kernel_launch(void* const* d_in, const int* in_sizes, int n_in,
                              void* d_out, int out_size, void* d_ws, size_t ws_size,
                              hipStream_t stream) {
    const float* x     = (const float*)d_in[0];
    const float* embed = (const float*)d_in[1];

    float* out     = (float*)d_out;
    float* quant   = out;                            // [N, D]
    float* ind_out = out + (size_t)N_ROWS * DIM;     // [N] (as float)
    float* cs      = ind_out + N_ROWS;               // [K]
    float* esum    = cs + K_CODES;                   // [K, D]  (contiguous w/ cs)

    // ws: e2 [K] | cnt [4 ints] | list [N] | ind_ws [N] | e2h [K]  (~1.07 MB)
    float* e2   = (float*)d_ws;
    int* cnt    = (int*)(e2 + K_CODES);
    int* list   = cnt + 4;
    int* ind_ws = list + N_ROWS;
    float* e2h  = (float*)(ind_ws + N_ROWS);

    // bf16 hi/lo packed embed lives in the quant region of d_out (1 MB);
    // nothing reads it after dist, and scatter fully overwrites quant later.
    unsigned short* ebf = (unsigned short*)quant;

    pack_kernel<<<(K_CODES * 16) / 256, 256, 0, stream>>>(
        embed, ebf, e2, e2h, cnt, cs);
    dist_argmin_kernel<<<N_ROWS / BROWS, 256, 0, stream>>>(
        x, ebf, e2h, ind_ws, ind_out, cnt, list);
    refine_kernel<<<512, 256, 0, stream>>>(x, embed, e2, cnt, list, ind_ws, ind_out);
    scatter_kernel<<<(size_t)N_ROWS * DIM / 256, 256, 0, stream>>>(
        x, embed, ind_ws, quant, cs, esum);
}

// Round 6
// 436.820 us; speedup vs baseline: 4.6934x; 1.0149x over previous
//
#include <hip/hip_runtime.h>

#define N_ROWS 131072
#define DIM 64
#define K_CODES 4096
#define BROWS 256            // rows per block = 4 waves x 64
#define CK 64                // cols per chunk
#define NCH (K_CODES / CK)   // 64 chunks
#define EST 72               // LDS bf16 stride (64 + 8 pad) -> bank-balanced frags
#define EPS 0.015625f        // flag margin in score space (>=15x bf16x3 error bound)
#define HEPS 0.0078125f      // EPS/2 in d-space (score = -2*d + const)

typedef __attribute__((ext_vector_type(8))) short short8;
typedef __attribute__((ext_vector_type(4))) float f32x4;

__device__ inline unsigned short bf16rn(float f) {      // round-nearest-even
    unsigned int u = __float_as_uint(f);
    u += 0x7FFFu + ((u >> 16) & 1u);
    return (unsigned short)(u >> 16);
}
// order-preserving float -> uint32 (finite scores)
__device__ inline unsigned int fkey(float f) {
    unsigned int u = __float_as_uint(f);
    return (u & 0x80000000u) ? ~u : (u | 0x80000000u);
}

// ---- pack embed -> bf16 hi/lo [code][hi 64 | lo 64], plus e2 / -e2/2, plus
//      zero-fill of cnt and the cs/esum output stats.
// Plain row-major, no swizzle: LDS contents in dist stay BIT-IDENTICAL to the
// proven round-4/5 kernel (rounds 1-3's swizzled staging inflated the
// ambiguity-flag count ~100x -> that path stays dead).
__global__ void pack_kernel(const float* __restrict__ embed,
                            unsigned short* __restrict__ ebf,
                            float* __restrict__ e2,       // exact, for refine
                            float* __restrict__ e2h,      // -e2/2, for dist init
                            int* __restrict__ cnt,
                            float* __restrict__ cs) {     // cs..esum contiguous
    const int g = blockIdx.x * blockDim.x + threadIdx.x;   // K*16 = 65536 thr
    // zero stats: cs [K] followed contiguously by esum [K*D]
    for (int i = g; i < K_CODES + K_CODES * DIM; i += K_CODES * 16)
        cs[i] = 0.f;
    if (g == 0) *cnt = 0;

    const int code = g >> 4;                               // 16 granules / code
    const int w    = g & 15;
    const int half = w >> 3;                               // 0 = hi, 1 = lo
    const int d0   = (w & 7) << 3;                         // dim 0..56
    const float* ep = embed + (size_t)code * DIM + d0;
    float4 f0 = *(const float4*)ep;
    float4 f1 = *(const float4*)(ep + 4);
    float wv[8] = {f0.x, f0.y, f0.z, f0.w, f1.x, f1.y, f1.z, f1.w};
    unsigned short o[8];
    float ssq = 0.f;
#pragma unroll
    for (int j = 0; j < 8; ++j) {
        unsigned short hb = bf16rn(wv[j]);
        if (half == 0) {
            o[j] = hb;
            ssq = fmaf(wv[j], wv[j], ssq);
        } else {
            float hf = __uint_as_float(((unsigned int)hb) << 16);
            o[j] = bf16rn(wv[j] - hf);
        }
    }
    *(uint4*)(ebf + (size_t)code * 128 + half * 64 + d0) = *(uint4*)o;
    // e2: reduce ssq across the 8 hi-granule lanes of this code
    ssq += __shfl_xor(ssq, 1, 64);
    ssq += __shfl_xor(ssq, 2, 64);
    ssq += __shfl_xor(ssq, 4, 64);
    if (w == 0) {
        e2[code]  = ssq;
        e2h[code] = -0.5f * ssq;
    }
}

// ---- MFMA distance + fused top-2 argmax(d), d = x.e - e2/2 ----
// r6 change: reg-staged double-buffered LDS, ONE barrier per chunk
// (T14 issue-early/write-late). Per-buffer LDS contents and all MFMA inputs
// are bit-identical to the proven r5 kernel; only the schedule changes.
__global__ __launch_bounds__(256, 2) void dist_argmin_kernel(
        const float* __restrict__ x, const unsigned short* __restrict__ ebf,
        const float* __restrict__ e2h, int* __restrict__ ind_ws,
        float* __restrict__ ind_out, int* __restrict__ cnt,
        int* __restrict__ list) {
    __shared__ unsigned short esh[2][CK * EST];   // 2 x 9216 B
    __shared__ unsigned short esl[2][CK * EST];   // 2 x 9216 B
    __shared__ float e2s[2][CK];                  // holds -e2/2

    const int tid  = threadIdx.x;
    const int l15  = tid & 15;
    const int quad = (tid >> 4) & 3;
    const int wave = tid >> 6;
    const int r0w  = blockIdx.x * BROWS + wave * 64;

    const int col = tid >> 2;          // staging: code within chunk
    const int dq  = (tid & 3) * 16;    // staging: dim offset (16 bf16)

    // ---- prologue: issue chunk-0 global loads FIRST (fly under A-frag conv)
    uint4 sh0, sh1, sl0, sl1;
    float se2 = 0.f;
    {
        const unsigned short* pp = ebf + (size_t)col * 128 + dq;
        sh0 = *(const uint4*)pp;
        sh1 = *(const uint4*)(pp + 8);
        sl0 = *(const uint4*)(pp + 64);
        sl1 = *(const uint4*)(pp + 72);
        if (tid < CK) se2 = e2h[tid];
    }

    // A-frags: A[m=l15][k=quad*8+j] per 16x16x32; rows 16i+l15, k-windows 32s+8q
    short8 ah[4][2], al[4][2];
#pragma unroll
    for (int i = 0; i < 4; ++i)
#pragma unroll
        for (int s = 0; s < 2; ++s) {
            const float* xp = x + (size_t)(r0w + 16 * i + l15) * DIM + 32 * s + 8 * quad;
            float4 f0 = *(const float4*)xp;
            float4 f1 = *(const float4*)(xp + 4);
            float w[8] = {f0.x, f0.y, f0.z, f0.w, f1.x, f1.y, f1.z, f1.w};
            short8 h, l;
#pragma unroll
            for (int j = 0; j < 8; ++j) {
                unsigned short hb = bf16rn(w[j]);
                float hf = __uint_as_float(((unsigned int)hb) << 16);
                h[j] = (short)hb;
                l[j] = (short)bf16rn(w[j] - hf);
            }
            ah[i][s] = h;
            al[i][s] = l;
        }

    // write chunk 0 into buffer 0
    *(uint4*)(&esh[0][col * EST + dq])     = sh0;
    *(uint4*)(&esh[0][col * EST + dq + 8]) = sh1;
    *(uint4*)(&esl[0][col * EST + dq])     = sl0;
    *(uint4*)(&esl[0][col * EST + dq + 8]) = sl1;
    if (tid < CK) e2s[0][tid] = se2;

    float s1[16], s2[16];
    int c1[16];
#pragma unroll
    for (int t = 0; t < 16; ++t) { s1[t] = -3.4e38f; s2[t] = -3.4e38f; c1[t] = 0; }

    __syncthreads();   // buffer 0 ready

    int cur = 0;
    for (int ch = 0; ch < NCH; ++ch) {
        // ---- issue next chunk's global loads early (wraps to 0 harmlessly)
        {
            const int c0n = ((ch + 1) & (NCH - 1)) * CK;
            const unsigned short* pp = ebf + (size_t)(c0n + col) * 128 + dq;
            sh0 = *(const uint4*)pp;
            sh1 = *(const uint4*)(pp + 8);
            sl0 = *(const uint4*)(pp + 64);
            sl1 = *(const uint4*)(pp + 72);
            if (tid < CK) se2 = e2h[c0n + tid];
        }

        const int c0 = ch * CK;

        // acc init = -e2[col]/2 (C/D col = l15 per 16-tile j)
        f32x4 acc[4][4];
#pragma unroll
        for (int j = 0; j < 4; ++j) {
            const float ev = e2s[cur][16 * j + l15];
            const f32x4 iv = {ev, ev, ev, ev};
#pragma unroll
            for (int i = 0; i < 4; ++i) acc[i][j] = iv;
        }

#pragma unroll
        for (int j = 0; j < 4; ++j) {
            const int cb = (16 * j + l15) * EST + 8 * quad;   // B[n=l15][k=8q+j]
            short8 bh0 = *(const short8*)(&esh[cur][cb]);
            short8 bh1 = *(const short8*)(&esh[cur][cb + 32]);
            short8 bl0 = *(const short8*)(&esl[cur][cb]);
            short8 bl1 = *(const short8*)(&esl[cur][cb + 32]);
#pragma unroll
            for (int i = 0; i < 4; ++i) {
                f32x4 a = acc[i][j];
                a = __builtin_amdgcn_mfma_f32_16x16x32_bf16(ah[i][0], bh0, a, 0, 0, 0);
                a = __builtin_amdgcn_mfma_f32_16x16x32_bf16(ah[i][1], bh1, a, 0, 0, 0);
                a = __builtin_amdgcn_mfma_f32_16x16x32_bf16(ah[i][0], bl0, a, 0, 0, 0);
                a = __builtin_amdgcn_mfma_f32_16x16x32_bf16(ah[i][1], bl1, a, 0, 0, 0);
                a = __builtin_amdgcn_mfma_f32_16x16x32_bf16(al[i][0], bh0, a, 0, 0, 0);
                a = __builtin_amdgcn_mfma_f32_16x16x32_bf16(al[i][1], bh1, a, 0, 0, 0);
                acc[i][j] = a;
            }
        }

        // epilogue (unchanged from r5, proven): argmax d, clamp-idiom s2
#pragma unroll
        for (int j = 0; j < 4; ++j) {
            const int c = c0 + 16 * j + l15;
#pragma unroll
            for (int i = 0; i < 4; ++i)
#pragma unroll
                for (int r = 0; r < 4; ++r) {
                    float d = acc[i][j][r];
                    const int st = i * 4 + r;
                    bool gt = d > s1[st];
                    s2[st] = fmaxf(fminf(d, s1[st]), s2[st]);
                    c1[st] = gt ? c : c1[st];
                    s1[st] = fmaxf(s1[st], d);
                }
        }

        // ---- write next chunk into the inactive buffer (nobody reads it now)
        const int nxt = cur ^ 1;
        *(uint4*)(&esh[nxt][col * EST + dq])     = sh0;
        *(uint4*)(&esh[nxt][col * EST + dq + 8]) = sh1;
        *(uint4*)(&esl[nxt][col * EST + dq])     = sl0;
        *(uint4*)(&esl[nxt][col * EST + dq + 8]) = sl1;
        if (tid < CK) e2s[nxt][tid] = se2;

        __syncthreads();   // next buffer visible; all waves done with cur
        cur = nxt;
    }

    // butterfly top-2 merge across the 16 lanes (same quad) sharing each row
#pragma unroll
    for (int st = 0; st < 16; ++st) {
#pragma unroll
        for (int m = 1; m < 16; m <<= 1) {
            float os1 = __shfl_xor(s1[st], m, 64);
            float os2 = __shfl_xor(s2[st], m, 64);
            int   oc1 = __shfl_xor(c1[st], m, 64);
            bool take = (os1 > s1[st]) || (os1 == s1[st] && oc1 < c1[st]);
            float loser = take ? s1[st] : os1;
            s2[st] = fmaxf(fmaxf(s2[st], os2), loser);
            if (take) { s1[st] = os1; c1[st] = oc1; }
        }
    }
    if (l15 == 0) {
#pragma unroll
        for (int st = 0; st < 16; ++st) {
            const int i = st >> 2, r = st & 3;
            const int row = r0w + 16 * i + 4 * quad + r;
            ind_ws[row] = c1[st];
            ind_out[row] = (float)c1[st];
            if (s1[st] - s2[st] < HEPS) {    // d-gap = score-gap/2 < EPS/2
                int p = atomicAdd(cnt, 1);
                list[p] = row;
            }
        }
    }
}

// ---- exact fp32 re-solve for flagged rows (block per row, round-0 proven) ----
__global__ void refine_kernel(const float* __restrict__ x,
                              const float* __restrict__ embed,
                              const float* __restrict__ e2g,
                              const int* __restrict__ cnt,
                              const int* __restrict__ list,
                              int* __restrict__ ind_ws,
                              float* __restrict__ ind_out) {
    __shared__ float xr[DIM];
    __shared__ unsigned long long red[256];
    const int tid = threadIdx.x;
    const int n = *cnt;
    for (int f = blockIdx.x; f < n; f += gridDim.x) {
        const int row = list[f];
        __syncthreads();
        if (tid < 16)
            ((float4*)xr)[tid] = ((const float4*)(x + (size_t)row * DIM))[tid];
        __syncthreads();
        unsigned long long best = ~0ull;
        for (int c = tid; c < K_CODES; c += 256) {
            const float4* ep = (const float4*)(embed + (size_t)c * DIM);
            float d0 = 0.f, d1 = 0.f, d2 = 0.f, d3 = 0.f;
#pragma unroll
            for (int q = 0; q < 16; ++q) {
                float4 ev = ep[q];
                d0 = fmaf(xr[4 * q + 0], ev.x, d0);
                d1 = fmaf(xr[4 * q + 1], ev.y, d1);
                d2 = fmaf(xr[4 * q + 2], ev.z, d2);
                d3 = fmaf(xr[4 * q + 3], ev.w, d3);
            }
            float sc = fmaf(-2.f, (d0 + d1) + (d2 + d3), e2g[c]);
            unsigned long long key =
                ((unsigned long long)fkey(sc) << 32) | (unsigned int)c;
            if (key < best) best = key;
        }
        red[tid] = best;
        __syncthreads();
        for (int w = 128; w > 0; w >>= 1) {
            if (tid < w && red[tid + w] < red[tid]) red[tid] = red[tid + w];
            __syncthreads();
        }
        if (tid == 0) {
            int k = (int)(red[0] & 0xFFFFFFFFull);
            ind_ws[row] = k;
            ind_out[row] = (float)k;
        }
    }
}

// ---- gather quantize + scatter stats (one wave = one row) ----
__global__ void scatter_kernel(const float* __restrict__ x,
                               const float* __restrict__ embed,
                               const int* __restrict__ ind,
                               float* __restrict__ quant,
                               float* __restrict__ cs,
                               float* __restrict__ esum) {
    const int t = blockIdx.x * blockDim.x + threadIdx.x;
    const int row = t >> 6;
    const int d = t & 63;
    const int k = ind[row];
    quant[t] = embed[(size_t)k * DIM + d];
    atomicAdd(&esum[(size_t)k * DIM + d], x[t]);
    if (d == 0) atomicAdd(&cs[k], 1.0f);
}

extern "C" void kernel_launch(void* const* d_in, const int* in_sizes, int n_in,
                              void* d_out, int out_size, void* d_ws, size_t ws_size,
                              hipStream_t stream) {
    const float* x     = (const float*)d_in[0];
    const float* embed = (const float*)d_in[1];

    float* out     = (float*)d_out;
    float* quant   = out;                            // [N, D]
    float* ind_out = out + (size_t)N_ROWS * DIM;     // [N] (as float)
    float* cs      = ind_out + N_ROWS;               // [K]
    float* esum    = cs + K_CODES;                   // [K, D]  (contiguous w/ cs)

    // ws: e2 [K] | cnt [4 ints] | list [N] | ind_ws [N] | e2h [K]  (~1.07 MB)
    float* e2   = (float*)d_ws;
    int* cnt    = (int*)(e2 + K_CODES);
    int* list   = cnt + 4;
    int* ind_ws = list + N_ROWS;
    float* e2h  = (float*)(ind_ws + N_ROWS);

    // bf16 hi/lo packed embed lives in the quant region of d_out (1 MB);
    // nothing reads it after dist, and scatter fully overwrites quant later.
    unsigned short* ebf = (unsigned short*)quant;

    pack_kernel<<<(K_CODES * 16) / 256, 256, 0, stream>>>(
        embed, ebf, e2, e2h, cnt, cs);
    dist_argmin_kernel<<<N_ROWS / BROWS, 256, 0, stream>>>(
        x, ebf, e2h, ind_ws, ind_out, cnt, list);
    refine_kernel<<<512, 256, 0, stream>>>(x, embed, e2, cnt, list, ind_ws, ind_out);
    scatter_kernel<<<(size_t)N_ROWS * DIM / 256, 256, 0, stream>>>(
        x, embed, ind_ws, quant, cs, esum);
}

// Round 7
// 402.544 us; speedup vs baseline: 5.0931x; 1.0852x over previous
//
#include <hip/hip_runtime.h>

#define N_ROWS 131072
#define DIM 64
#define K_CODES 4096
#define BROWS 256            // rows per block = 4 waves x 64
#define CK 64                // cols per chunk
#define NCH (K_CODES / CK)   // 64 chunks
#define EST 72               // LDS bf16 stride (64 + 8 pad) -> bank-balanced frags
#define EPS 0.015625f        // flag margin in score space (>=15x bf16x3 error bound)
#define HEPS 0.0078125f      // EPS/2 in d-space (score = -2*d + const)

typedef __attribute__((ext_vector_type(8))) short short8;
typedef __attribute__((ext_vector_type(4))) float f32x4;

__device__ inline unsigned short bf16rn(float f) {      // round-nearest-even
    unsigned int u = __float_as_uint(f);
    u += 0x7FFFu + ((u >> 16) & 1u);
    return (unsigned short)(u >> 16);
}
// order-preserving float -> uint32 (finite scores)
__device__ inline unsigned int fkey(float f) {
    unsigned int u = __float_as_uint(f);
    return (u & 0x80000000u) ? ~u : (u | 0x80000000u);
}

// ---- pack embed -> bf16 hi/lo [code][hi 64 | lo 64], plus e2 / -e2/2, plus
//      zero-fill of cnt and the cs/esum output stats.
// Plain row-major, no swizzle: LDS contents in dist stay BIT-IDENTICAL to the
// proven round-4/5/6 kernel (rounds 1-3's swizzled staging inflated the
// ambiguity-flag count ~100x -> that path stays dead).
__global__ void pack_kernel(const float* __restrict__ embed,
                            unsigned short* __restrict__ ebf,
                            float* __restrict__ e2,       // exact, for refine
                            float* __restrict__ e2h,      // -e2/2, for dist init
                            int* __restrict__ cnt,
                            float* __restrict__ cs) {     // cs..esum contiguous
    const int g = blockIdx.x * blockDim.x + threadIdx.x;   // K*16 = 65536 thr
    // zero stats: cs [K] followed contiguously by esum [K*D]
    for (int i = g; i < K_CODES + K_CODES * DIM; i += K_CODES * 16)
        cs[i] = 0.f;
    if (g == 0) *cnt = 0;

    const int code = g >> 4;                               // 16 granules / code
    const int w    = g & 15;
    const int half = w >> 3;                               // 0 = hi, 1 = lo
    const int d0   = (w & 7) << 3;                         // dim 0..56
    const float* ep = embed + (size_t)code * DIM + d0;
    float4 f0 = *(const float4*)ep;
    float4 f1 = *(const float4*)(ep + 4);
    float wv[8] = {f0.x, f0.y, f0.z, f0.w, f1.x, f1.y, f1.z, f1.w};
    unsigned short o[8];
    float ssq = 0.f;
#pragma unroll
    for (int j = 0; j < 8; ++j) {
        unsigned short hb = bf16rn(wv[j]);
        if (half == 0) {
            o[j] = hb;
            ssq = fmaf(wv[j], wv[j], ssq);
        } else {
            float hf = __uint_as_float(((unsigned int)hb) << 16);
            o[j] = bf16rn(wv[j] - hf);
        }
    }
    *(uint4*)(ebf + (size_t)code * 128 + half * 64 + d0) = *(uint4*)o;
    // e2: reduce ssq across the 8 hi-granule lanes of this code
    ssq += __shfl_xor(ssq, 1, 64);
    ssq += __shfl_xor(ssq, 2, 64);
    ssq += __shfl_xor(ssq, 4, 64);
    if (w == 0) {
        e2[code]  = ssq;
        e2h[code] = -0.5f * ssq;
    }
}

// ---- MFMA distance + fused top-2 argmax(d), d = x.e - e2/2 ----
// r6 schedule: reg-staged double-buffered LDS, ONE barrier per chunk.
// r7 change: when fused!=0, append the gather/scatter epilogue (quant write,
// esum/cs atomics) so its VMEM traffic overlaps other blocks' MFMA work —
// dist runs at ~1% HBM so the capacity is free. Score math untouched.
__global__ __launch_bounds__(256, 2) void dist_argmin_kernel(
        const float* __restrict__ x, const unsigned short* __restrict__ ebf,
        const float* __restrict__ e2h, const float* __restrict__ embed,
        int* __restrict__ ind_ws, float* __restrict__ ind_out,
        int* __restrict__ cnt, int* __restrict__ list,
        float* __restrict__ quant, float* __restrict__ cs,
        float* __restrict__ esum, int fused) {
    __shared__ unsigned short esh[2][CK * EST];   // 2 x 9216 B
    __shared__ unsigned short esl[2][CK * EST];   // 2 x 9216 B
    __shared__ float e2s[2][CK];                  // holds -e2/2

    const int tid  = threadIdx.x;
    const int l15  = tid & 15;
    const int quad = (tid >> 4) & 3;
    const int wave = tid >> 6;
    const int r0w  = blockIdx.x * BROWS + wave * 64;

    const int col = tid >> 2;          // staging: code within chunk
    const int dq  = (tid & 3) * 16;    // staging: dim offset (16 bf16)

    // ---- prologue: issue chunk-0 global loads FIRST (fly under A-frag conv)
    uint4 sh0, sh1, sl0, sl1;
    float se2 = 0.f;
    {
        const unsigned short* pp = ebf + (size_t)col * 128 + dq;
        sh0 = *(const uint4*)pp;
        sh1 = *(const uint4*)(pp + 8);
        sl0 = *(const uint4*)(pp + 64);
        sl1 = *(const uint4*)(pp + 72);
        if (tid < CK) se2 = e2h[tid];
    }

    // A-frags: A[m=l15][k=quad*8+j] per 16x16x32; rows 16i+l15, k-windows 32s+8q
    short8 ah[4][2], al[4][2];
#pragma unroll
    for (int i = 0; i < 4; ++i)
#pragma unroll
        for (int s = 0; s < 2; ++s) {
            const float* xp = x + (size_t)(r0w + 16 * i + l15) * DIM + 32 * s + 8 * quad;
            float4 f0 = *(const float4*)xp;
            float4 f1 = *(const float4*)(xp + 4);
            float w[8] = {f0.x, f0.y, f0.z, f0.w, f1.x, f1.y, f1.z, f1.w};
            short8 h, l;
#pragma unroll
            for (int j = 0; j < 8; ++j) {
                unsigned short hb = bf16rn(w[j]);
                float hf = __uint_as_float(((unsigned int)hb) << 16);
                h[j] = (short)hb;
                l[j] = (short)bf16rn(w[j] - hf);
            }
            ah[i][s] = h;
            al[i][s] = l;
        }

    // write chunk 0 into buffer 0
    *(uint4*)(&esh[0][col * EST + dq])     = sh0;
    *(uint4*)(&esh[0][col * EST + dq + 8]) = sh1;
    *(uint4*)(&esl[0][col * EST + dq])     = sl0;
    *(uint4*)(&esl[0][col * EST + dq + 8]) = sl1;
    if (tid < CK) e2s[0][tid] = se2;

    float s1[16], s2[16];
    int c1[16];
#pragma unroll
    for (int t = 0; t < 16; ++t) { s1[t] = -3.4e38f; s2[t] = -3.4e38f; c1[t] = 0; }

    __syncthreads();   // buffer 0 ready

    int cur = 0;
    for (int ch = 0; ch < NCH; ++ch) {
        // ---- issue next chunk's global loads early (wraps to 0 harmlessly)
        {
            const int c0n = ((ch + 1) & (NCH - 1)) * CK;
            const unsigned short* pp = ebf + (size_t)(c0n + col) * 128 + dq;
            sh0 = *(const uint4*)pp;
            sh1 = *(const uint4*)(pp + 8);
            sl0 = *(const uint4*)(pp + 64);
            sl1 = *(const uint4*)(pp + 72);
            if (tid < CK) se2 = e2h[c0n + tid];
        }

        const int c0 = ch * CK;

        // acc init = -e2[col]/2 (C/D col = l15 per 16-tile j)
        f32x4 acc[4][4];
#pragma unroll
        for (int j = 0; j < 4; ++j) {
            const float ev = e2s[cur][16 * j + l15];
            const f32x4 iv = {ev, ev, ev, ev};
#pragma unroll
            for (int i = 0; i < 4; ++i) acc[i][j] = iv;
        }

#pragma unroll
        for (int j = 0; j < 4; ++j) {
            const int cb = (16 * j + l15) * EST + 8 * quad;   // B[n=l15][k=8q+j]
            short8 bh0 = *(const short8*)(&esh[cur][cb]);
            short8 bh1 = *(const short8*)(&esh[cur][cb + 32]);
            short8 bl0 = *(const short8*)(&esl[cur][cb]);
            short8 bl1 = *(const short8*)(&esl[cur][cb + 32]);
#pragma unroll
            for (int i = 0; i < 4; ++i) {
                f32x4 a = acc[i][j];
                a = __builtin_amdgcn_mfma_f32_16x16x32_bf16(ah[i][0], bh0, a, 0, 0, 0);
                a = __builtin_amdgcn_mfma_f32_16x16x32_bf16(ah[i][1], bh1, a, 0, 0, 0);
                a = __builtin_amdgcn_mfma_f32_16x16x32_bf16(ah[i][0], bl0, a, 0, 0, 0);
                a = __builtin_amdgcn_mfma_f32_16x16x32_bf16(ah[i][1], bl1, a, 0, 0, 0);
                a = __builtin_amdgcn_mfma_f32_16x16x32_bf16(al[i][0], bh0, a, 0, 0, 0);
                a = __builtin_amdgcn_mfma_f32_16x16x32_bf16(al[i][1], bh1, a, 0, 0, 0);
                acc[i][j] = a;
            }
        }

        // epilogue (proven): argmax d, clamp-idiom second-max
#pragma unroll
        for (int j = 0; j < 4; ++j) {
            const int c = c0 + 16 * j + l15;
#pragma unroll
            for (int i = 0; i < 4; ++i)
#pragma unroll
                for (int r = 0; r < 4; ++r) {
                    float d = acc[i][j][r];
                    const int st = i * 4 + r;
                    bool gt = d > s1[st];
                    s2[st] = fmaxf(fminf(d, s1[st]), s2[st]);
                    c1[st] = gt ? c : c1[st];
                    s1[st] = fmaxf(s1[st], d);
                }
        }

        // ---- write next chunk into the inactive buffer
        const int nxt = cur ^ 1;
        *(uint4*)(&esh[nxt][col * EST + dq])     = sh0;
        *(uint4*)(&esh[nxt][col * EST + dq + 8]) = sh1;
        *(uint4*)(&esl[nxt][col * EST + dq])     = sl0;
        *(uint4*)(&esl[nxt][col * EST + dq + 8]) = sl1;
        if (tid < CK) e2s[nxt][tid] = se2;

        __syncthreads();   // next buffer visible; all waves done with cur
        cur = nxt;
    }

    // butterfly top-2 merge across the 16 lanes (same quad) sharing each row
#pragma unroll
    for (int st = 0; st < 16; ++st) {
#pragma unroll
        for (int m = 1; m < 16; m <<= 1) {
            float os1 = __shfl_xor(s1[st], m, 64);
            float os2 = __shfl_xor(s2[st], m, 64);
            int   oc1 = __shfl_xor(c1[st], m, 64);
            bool take = (os1 > s1[st]) || (os1 == s1[st] && oc1 < c1[st]);
            float loser = take ? s1[st] : os1;
            s2[st] = fmaxf(fmaxf(s2[st], os2), loser);
            if (take) { s1[st] = os1; c1[st] = oc1; }
        }
    }
    if (l15 == 0) {
#pragma unroll
        for (int st = 0; st < 16; ++st) {
            const int i = st >> 2, r = st & 3;
            const int row = r0w + 16 * i + 4 * quad + r;
            ind_ws[row] = c1[st];
            ind_out[row] = (float)c1[st];
            if (s1[st] - s2[st] < HEPS) {    // d-gap = score-gap/2 < EPS/2
                int p = atomicAdd(cnt, 1);
                list[p] = row;
            }
        }
    }

    // ---- fused gather/scatter epilogue (replaces scatter_kernel) ----
    // All waves are past the final barrier; esh is dead -> reuse as an
    // intra-wave index board (each wave touches only its own 256 B).
    if (fused) {
        int* li = (int*)&esh[0][0];
        if (l15 == 0) {
#pragma unroll
            for (int st = 0; st < 16; ++st) {
                const int i = st >> 2, r = st & 3;
                li[(wave << 6) + 16 * i + 4 * quad + r] = c1[st];
            }
        }
        const int lane = tid & 63;
        for (int t = 0; t < 64; ++t) {
            const int k = li[(wave << 6) + t];   // wave-uniform broadcast read
            const size_t row = (size_t)(r0w + t);
            quant[row * DIM + lane] = embed[(size_t)k * DIM + lane];
            float xv = x[row * DIM + lane];      // L3-hot (read earlier)
            atomicAdd(&esum[(size_t)k * DIM + lane], xv);
            if (lane == 0) atomicAdd(&cs[k], 1.0f);
        }
    }
}

// ---- exact fp32 re-solve for flagged rows (block per row, round-0 proven) ----
// fused mode: also FIX UP quant/cs/esum for rows whose index changed
// (subtract old contribution, add new; x row is in LDS, exact fp32).
__global__ void refine_kernel(const float* __restrict__ x,
                              const float* __restrict__ embed,
                              const float* __restrict__ e2g,
                              const int* __restrict__ cnt,
                              const int* __restrict__ list,
                              int* __restrict__ ind_ws,
                              float* __restrict__ ind_out,
                              float* __restrict__ quant,
                              float* __restrict__ cs,
                              float* __restrict__ esum, int fused) {
    __shared__ float xr[DIM];
    __shared__ unsigned long long red[256];
    const int tid = threadIdx.x;
    const int n = *cnt;
    for (int f = blockIdx.x; f < n; f += gridDim.x) {
        const int row = list[f];
        __syncthreads();
        if (tid < 16)
            ((float4*)xr)[tid] = ((const float4*)(x + (size_t)row * DIM))[tid];
        __syncthreads();
        unsigned long long best = ~0ull;
        for (int c = tid; c < K_CODES; c += 256) {
            const float4* ep = (const float4*)(embed + (size_t)c * DIM);
            float d0 = 0.f, d1 = 0.f, d2 = 0.f, d3 = 0.f;
#pragma unroll
            for (int q = 0; q < 16; ++q) {
                float4 ev = ep[q];
                d0 = fmaf(xr[4 * q + 0], ev.x, d0);
                d1 = fmaf(xr[4 * q + 1], ev.y, d1);
                d2 = fmaf(xr[4 * q + 2], ev.z, d2);
                d3 = fmaf(xr[4 * q + 3], ev.w, d3);
            }
            float sc = fmaf(-2.f, (d0 + d1) + (d2 + d3), e2g[c]);
            unsigned long long key =
                ((unsigned long long)fkey(sc) << 32) | (unsigned int)c;
            if (key < best) best = key;
        }
        red[tid] = best;
        __syncthreads();
        for (int w = 128; w > 0; w >>= 1) {
            if (tid < w && red[tid + w] < red[tid]) red[tid] = red[tid + w];
            __syncthreads();
        }
        const int k_new = (int)(red[0] & 0xFFFFFFFFull);
        if (fused) {
            const int k_old = ind_ws[row];
            if (k_new != k_old) {
                if (tid < DIM) {
                    float xv = xr[tid];
                    atomicAdd(&esum[(size_t)k_old * DIM + tid], -xv);
                    atomicAdd(&esum[(size_t)k_new * DIM + tid],  xv);
                    quant[(size_t)row * DIM + tid] =
                        embed[(size_t)k_new * DIM + tid];
                }
                if (tid == 0) {
                    atomicAdd(&cs[k_old], -1.f);
                    atomicAdd(&cs[k_new],  1.f);
                    ind_ws[row] = k_new;
                    ind_out[row] = (float)k_new;
                }
            }
        } else if (tid == 0) {
            ind_ws[row] = k_new;
            ind_out[row] = (float)k_new;
        }
    }
}

// ---- gather quantize + scatter stats (fallback only, one wave = one row) ----
__global__ void scatter_kernel(const float* __restrict__ x,
                               const float* __restrict__ embed,
                               const int* __restrict__ ind,
                               float* __restrict__ quant,
                               float* __restrict__ cs,
                               float* __restrict__ esum) {
    const int t = blockIdx.x * blockDim.x + threadIdx.x;
    const int row = t >> 6;
    const int d = t & 63;
    const int k = ind[row];
    quant[t] = embed[(size_t)k * DIM + d];
    atomicAdd(&esum[(size_t)k * DIM + d], x[t]);
    if (d == 0) atomicAdd(&cs[k], 1.0f);
}

extern "C" void kernel_launch(void* const* d_in, const int* in_sizes, int n_in,
                              void* d_out, int out_size, void* d_ws, size_t ws_size,
                              hipStream_t stream) {
    const float* x     = (const float*)d_in[0];
    const float* embed = (const float*)d_in[1];

    float* out     = (float*)d_out;
    float* quant   = out;                            // [N, D]
    float* ind_out = out + (size_t)N_ROWS * DIM;     // [N] (as float)
    float* cs      = ind_out + N_ROWS;               // [K]
    float* esum    = cs + K_CODES;                   // [K, D]  (contiguous w/ cs)

    // ws: e2 [K] | cnt [4] | list [N] | ind_ws [N] | e2h [K] | ebf [K*128 u16]
    float* e2   = (float*)d_ws;
    int* cnt    = (int*)(e2 + K_CODES);
    int* list   = cnt + 4;
    int* ind_ws = list + N_ROWS;
    float* e2h  = (float*)(ind_ws + N_ROWS);
    unsigned short* ebf_ws = (unsigned short*)(e2h + K_CODES);
    const size_t ws_need =
        (size_t)((char*)(ebf_ws + (size_t)K_CODES * 128) - (char*)d_ws);

    // fused mode needs ebf in ws (dist's fused epilogue writes the quant
    // region, which is where the fallback parks ebf). Host-side check; the
    // fallback path is bit-identical to the round-6 kernel.
    const int fused = (ws_size >= ws_need) ? 1 : 0;
    unsigned short* ebf = fused ? ebf_ws : (unsigned short*)quant;

    pack_kernel<<<(K_CODES * 16) / 256, 256, 0, stream>>>(
        embed, ebf, e2, e2h, cnt, cs);
    dist_argmin_kernel<<<N_ROWS / BROWS, 256, 0, stream>>>(
        x, ebf, e2h, embed, ind_ws, ind_out, cnt, list, quant, cs, esum, fused);
    refine_kernel<<<512, 256, 0, stream>>>(
        x, embed, e2, cnt, list, ind_ws, ind_out, quant, cs, esum, fused);
    if (!fused)
        scatter_kernel<<<(size_t)N_ROWS * DIM / 256, 256, 0, stream>>>(
            x, embed, ind_ws, quant, cs, esum);
}